// Round 8
// baseline (267.393 us; speedup 1.0000x reference)
//
#include <hip/hip_runtime.h>
#include <hip/hip_bf16.h>

typedef __hip_bfloat16 bf16;
typedef __attribute__((ext_vector_type(8))) short short8;   // 8 bf16 = 4 VGPRs
typedef __attribute__((ext_vector_type(4))) float floatx4;  // MFMA C/D

#define SEQ 4096
#define DIM 1024
#define NH 16
#define HD 64

// exp2 directly on v_exp_f32 (Q is pre-scaled by log2(e)/8 in projection)
#if defined(__has_builtin)
#if __has_builtin(__builtin_amdgcn_exp2f)
#define EXP2(x) __builtin_amdgcn_exp2f(x)
#endif
#endif
#ifndef EXP2
#define EXP2(x) exp2f(x)
#endif

__device__ __forceinline__ short f2s(float f) { bf16 t = __float2bfloat16(f); return *(short*)&t; }

// async global->LDS, 16B per lane; LDS dest = wave-uniform base + lane*16
__device__ __forceinline__ void gload16(const void* g, void* l) {
    __builtin_amdgcn_global_load_lds(
        (const __attribute__((address_space(1))) void*)g,
        (__attribute__((address_space(3))) void*)l, 16, 0, 0);
}

// Barrier that orders LDS ops only (no vmcnt drain): in-flight global->REG
// prefetch loads legally cross it; their consumers get compiler-inserted
// counted vmcnt waits. Writes drained BEFORE s_barrier => cross-wave visible.
__device__ __forceinline__ void barrier_lgkm() {
    asm volatile("s_waitcnt lgkmcnt(0)" ::: "memory");
    __builtin_amdgcn_s_barrier();
}

__device__ __forceinline__ short8 cvt8(float4 a, float4 b) {
    short8 s;
    s[0] = f2s(a.x); s[1] = f2s(a.y); s[2] = f2s(a.z); s[3] = f2s(a.w);
    s[4] = f2s(b.x); s[5] = f2s(b.y); s[6] = f2s(b.z); s[7] = f2s(b.w);
    return s;
}

// ---------------------------------------------------------------------------
// Transpose+cast: W fp32 [K][N] -> Wt bf16 [N][K]. blockIdx.z selects weight.
// ---------------------------------------------------------------------------
__global__ __launch_bounds__(256) void transpose_cast_kernel(
    const float* __restrict__ W0, const float* __restrict__ W1,
    const float* __restrict__ W2, const float* __restrict__ W3,
    bf16* __restrict__ Wt_all)
{
    const float* W = blockIdx.z == 0 ? W0 : blockIdx.z == 1 ? W1
                   : blockIdx.z == 2 ? W2 : W3;
    bf16* Wt = Wt_all + (size_t)blockIdx.z * DIM * DIM;

    __shared__ float tile[32][33];
    const int n0 = blockIdx.x * 32, k0 = blockIdx.y * 32;
    const int tr = threadIdx.x >> 5;
    const int tc = threadIdx.x & 31;
#pragma unroll
    for (int i = 0; i < 32; i += 8)
        tile[tr + i][tc] = W[(size_t)(k0 + tr + i) * DIM + n0 + tc];
    __syncthreads();
#pragma unroll
    for (int i = 0; i < 32; i += 8)
        Wt[(size_t)(n0 + tr + i) * DIM + k0 + tc] = __float2bfloat16(tile[tc][tr + i]);
}

// ---------------------------------------------------------------------------
// Fused QKV GEMM (round-1 version, measured good): C_z = x(fp32) @ Wt_z^T.
// 128x128 tile, BK=64, fp32-A DMA staging + cvt at fragment read, XOR swizzle.
// z==0 (Q) output pre-scaled by log2(e)/sqrt(HD) so attention uses raw exp2.
// ---------------------------------------------------------------------------
#define QBM 128
#define QBN 128
#define QBK 64

__global__ __launch_bounds__(256) void qkv_gemm_kernel(
    const float* __restrict__ A, const bf16* __restrict__ Wt,
    bf16* __restrict__ Qb, bf16* __restrict__ Kb, bf16* __restrict__ Vb)
{
    const int z = blockIdx.z;
    const bf16* Bt = Wt + (size_t)z * DIM * DIM;
    bf16* C = z == 0 ? Qb : (z == 1 ? Kb : Vb);
    const float osc = (z == 0) ? 0.18033688f : 1.0f;   // 0.125 * log2(e)

    __shared__ alignas(16) float Af[QBM][QBK];   // 32 KB, fp32
    __shared__ alignas(16) short Bs[QBN][QBK];   // 16 KB, bf16

    const int tid  = threadIdx.x;
    const int wave = tid >> 6, lane = tid & 63;
    const int l15  = lane & 15, quad = lane >> 4;
    const int wm = (wave & 1) * 64;
    const int wn = (wave >> 1) * 64;
    const int bm = blockIdx.y * QBM;
    const int bn = blockIdx.x * QBN;

    const int arow = tid >> 4;
    const int agch = (tid & 15) ^ (arow & 15);
    const float* gA = A + (size_t)(bm + arow) * DIM + agch * 4;
    char* ldsA = (char*)&Af[0][0] + wave * 1024;

    const int brow = tid >> 3;
    const int bgch = (tid & 7) ^ (brow & 7);
    const bf16* gB = Bt + (size_t)(bn + brow) * DIM + bgch * 8;
    char* ldsB = (char*)&Bs[0][0] + wave * 1024;

    floatx4 acc[4][4] = {};

    for (int k0 = 0; k0 < DIM; k0 += QBK) {
        __syncthreads();
#pragma unroll
        for (int c = 0; c < 8; ++c)
            gload16(gA + (size_t)c * 16 * DIM + k0, ldsA + c * 4096);
#pragma unroll
        for (int c = 0; c < 4; ++c)
            gload16(gB + (size_t)c * 32 * DIM + k0, ldsB + c * 4096);
        __syncthreads();

#pragma unroll
        for (int c2 = 0; c2 < 2; ++c2) {
            const int g0 = c2 * 8 + quad * 2;
            const int cb = (c2 * 4 + quad) ^ (l15 & 7);
            short8 afr[4], bfr[4];
#pragma unroll
            for (int i = 0; i < 4; ++i) {
                const int ra = wm + i * 16 + l15;
                float4 f0 = *(const float4*)&Af[ra][(g0 ^ l15) * 4];
                float4 f1 = *(const float4*)&Af[ra][((g0 + 1) ^ l15) * 4];
                afr[i] = cvt8(f0, f1);
                bfr[i] = *(const short8*)&Bs[wn + i * 16 + l15][cb * 8];
            }
#pragma unroll
            for (int mi = 0; mi < 4; ++mi)
#pragma unroll
                for (int ni = 0; ni < 4; ++ni)
                    acc[mi][ni] = __builtin_amdgcn_mfma_f32_16x16x32_bf16(
                        afr[mi], bfr[ni], acc[mi][ni], 0, 0, 0);
        }
    }

#pragma unroll
    for (int mi = 0; mi < 4; ++mi)
#pragma unroll
        for (int r = 0; r < 4; ++r) {
            const int row = bm + wm + mi * 16 + quad * 4 + r;
#pragma unroll
            for (int ni = 0; ni < 4; ++ni) {
                const int col = bn + wn + ni * 16 + l15;
                C[(size_t)row * DIM + col] = __float2bfloat16(acc[mi][ni][r] * osc);
            }
        }
}

// ---------------------------------------------------------------------------
// Final GEMM (unchanged): out = ctx(bf16) @ Wo^T + bias. 128x64 tile.
// ---------------------------------------------------------------------------
__global__ __launch_bounds__(256) void out_gemm_kernel(
    const bf16* __restrict__ A, const bf16* __restrict__ Bt,
    const float* __restrict__ bias, float* __restrict__ C)
{
    __shared__ alignas(16) short Asl[128][64];
    __shared__ alignas(16) short Bsl[64][64];

    const int tid  = threadIdx.x;
    const int wave = tid >> 6, lane = tid & 63;
    const int l15  = lane & 15, quad = lane >> 4;
    const int wm = (wave & 1) * 64;
    const int wn = (wave >> 1) * 32;
    const int bm = blockIdx.y * 128;
    const int bn = blockIdx.x * 64;

    const int srow   = tid >> 3;
    const int gchunk = (tid & 7) ^ (srow & 7);
    const bf16* gA = A  + (size_t)(bm + srow) * DIM + gchunk * 8;
    const bf16* gB = Bt + (size_t)(bn + srow) * DIM + gchunk * 8;
    char* ldsA = (char*)&Asl[0][0] + wave * 1024;
    char* ldsB = (char*)&Bsl[0][0] + wave * 1024;

    floatx4 acc[4][2] = {};

    for (int k0 = 0; k0 < DIM; k0 += 64) {
        __syncthreads();
#pragma unroll
        for (int c = 0; c < 4; ++c)
            gload16(gA + (size_t)c * 32 * DIM + k0, ldsA + c * 4096);
#pragma unroll
        for (int c = 0; c < 2; ++c)
            gload16(gB + (size_t)c * 32 * DIM + k0, ldsB + c * 4096);
        __syncthreads();

#pragma unroll
        for (int c2 = 0; c2 < 2; ++c2) {
            const int cb = (c2 * 4 + quad) ^ (l15 & 7);
            short8 afr[4], bfr[2];
#pragma unroll
            for (int i = 0; i < 4; ++i)
                afr[i] = *(const short8*)&Asl[wm + i * 16 + l15][cb * 8];
#pragma unroll
            for (int i = 0; i < 2; ++i)
                bfr[i] = *(const short8*)&Bsl[wn + i * 16 + l15][cb * 8];
#pragma unroll
            for (int mi = 0; mi < 4; ++mi)
#pragma unroll
                for (int ni = 0; ni < 2; ++ni)
                    acc[mi][ni] = __builtin_amdgcn_mfma_f32_16x16x32_bf16(
                        afr[mi], bfr[ni], acc[mi][ni], 0, 0, 0);
        }
    }

#pragma unroll
    for (int mi = 0; mi < 4; ++mi)
#pragma unroll
        for (int r = 0; r < 4; ++r) {
            const int row = bm + wm + mi * 16 + quad * 4 + r;
#pragma unroll
            for (int ni = 0; ni < 2; ++ni) {
                const int col = bn + wn + ni * 16 + l15;
                C[(size_t)row * DIM + col] = acc[mi][ni][r] + bias[col];
            }
        }
}

// ---------------------------------------------------------------------------
// Flash attention v12 = round-6 structure with K READ DIRECTLY FROM GLOBAL.
// The QK fragment for lane (l15,quad) is K[key=n*16+l15][dims c*32+quad*8..+7]
// = 16B CONTIGUOUS in global K -- no transpose needed, so K never needed LDS.
// Each wave loads its kf[8] regs straight from L2 (K tile is 8KB, L2-hot:
// all 8 waves + partner block read the same lines). This removes half the
// per-tile LDS traffic (K reads + K staging writes + their bank conflicts)
// and moves it to the idle VMEM/L2 pipe, which overlaps with the V LDS reads.
// kf loads for tile kt+1 issue right after QK(kt): a full exp/PV phase
// (~800cy) to land. V path (reg-staged transpose, slot permutation,
// double-buffer, lgkm barriers), masking, pairing: unchanged from round 6.
// LDS: Vt only = 18.4 KB.
// ---------------------------------------------------------------------------
#define QT 128
#define KT 64
#define LDT 72

__global__ __launch_bounds__(512) void flash_attn_kernel(
    const bf16* __restrict__ Q, const bf16* __restrict__ K,
    const bf16* __restrict__ V, bf16* ctx)
{
    const int lin  = blockIdx.y * 32 + blockIdx.x;
    const int half = lin >> 8, idx = lin & 255;
    const int qj   = half ? (idx & 31) : 31 - (idx & 31);
    const int h    = (idx >> 5) + 8 * half;
    const int q0   = qj * QT;
    const int nkt  = 2 * qj + 2;

    const int tid  = threadIdx.x;          // 0..511
    const int wave = tid >> 6;             // 0..7, owns rows wave*16..+15
    const int lane = tid & 63;
    const int l15  = lane & 15;
    const int quad = lane >> 4;

    __shared__ alignas(16) short Vt[2][HD][LDT];      // 18.4 KB [buf][dim][slot]

    // ---- Q fragments straight from global (no LDS); 16 rows per wave ----
    short8 qfrag[2];
    {
        const bf16* qp = Q + (size_t)(q0 + wave * 16 + l15) * DIM
                       + h * HD + quad * 8;
        qfrag[0] = *(const short8*)(qp);
        qfrag[1] = *(const short8*)(qp + 32);
    }

    // ---- per-lane global K fragment base: row l15, dim chunk quad*8 ----
    const bf16* Kf = K + (size_t)l15 * DIM + h * HD + quad * 8;
    short8 kf[8];   // kf[n*2+c] = K[kbase + n*16 + l15][c*32 + quad*8 ..+7]
#define LOAD_KF(kb) do {                                                      \
    _Pragma("unroll")                                                         \
    for (int _n = 0; _n < 4; ++_n)                                            \
    _Pragma("unroll")                                                         \
    for (int _c = 0; _c < 2; ++_c)                                            \
        kf[_n * 2 + _c] = *(const short8*)                                    \
            (Kf + (size_t)((kb) + _n * 16) * DIM + _c * 32);                  \
} while (0)

    // V staging: threads 0..255 (keys vr,vr+1 x dims vd..vd+7)
    const bool vstager = tid < 256;
    const int vr = (tid & 31) * 2, vd = ((tid >> 5) & 7) * 8;
    // key -> PV k-slot permutation (slot bits [k5 k3 k2 k4 k1 k0]); vr even
    const int vslot = ((vr >> 5) & 1) * 32 + ((vr >> 2) & 3) * 8
                    + ((vr >> 4) & 1) * 4  + ((vr >> 1) & 1) * 2;

    // ---- tile 0: kf regs + V regs -> buf0 ----
    LOAD_KF(0);
    short8 vreg0, vreg1;
    if (vstager) {
        vreg0 = *(const short8*)(V + (size_t)vr * DIM + h * HD + vd);
        vreg1 = *(const short8*)(V + (size_t)(vr + 1) * DIM + h * HD + vd);
#pragma unroll
        for (int i = 0; i < 8; ++i) {
            unsigned int pv = (unsigned int)(unsigned short)vreg0[i]
                            | ((unsigned int)(unsigned short)vreg1[i] << 16);
            *(unsigned int*)&Vt[0][vd + i][vslot] = pv;
        }
        // prefetch tile 1 V regs (nkt >= 2 always)
        vreg0 = *(const short8*)(V + (size_t)(KT + vr) * DIM + h * HD + vd);
        vreg1 = *(const short8*)(V + (size_t)(KT + vr + 1) * DIM + h * HD + vd);
    }

    barrier_lgkm();   // buf0 ds_writes visible; prefetch loads stay in flight

    short8 onesf;
#pragma unroll
    for (int i = 0; i < 8; ++i) onesf[i] = (short)0x3F80;   // bf16 1.0

    floatx4 o_acc[4] = {};
    floatx4 lacc = {};

    for (int kt = 0; kt < nkt; ++kt) {
        const int b = kt & 1;

        // ---- S^T = K . Q^T : D[m=key n*16+quad*4+r][n=qrow l15] ----
        floatx4 sT[4] = {};
#pragma unroll
        for (int n = 0; n < 4; ++n)
#pragma unroll
            for (int c = 0; c < 2; ++c)
                sT[n] = __builtin_amdgcn_mfma_f32_16x16x32_bf16(
                    kf[n * 2 + c], qfrag[c], sT[n], 0, 0, 0);

        // ---- issue kf loads for tile kt+1 (L2-hot; lands during exp/PV) ----
        if (kt + 1 < nkt) LOAD_KF((size_t)(kt + 1) * KT);

        // ---- stage V tile kt+1 into buf[b^1]; prefetch V tile kt+2 ----
        if (kt + 1 < nkt && vstager) {
#pragma unroll
            for (int i = 0; i < 8; ++i) {
                unsigned int pv = (unsigned int)(unsigned short)vreg0[i]
                                | ((unsigned int)(unsigned short)vreg1[i] << 16);
                *(unsigned int*)&Vt[b ^ 1][vd + i][vslot] = pv;
            }
            if (kt + 2 < nkt) {
                const size_t nb = (size_t)(kt + 2) * KT;
                vreg0 = *(const short8*)(V + (nb + vr) * DIM + h * HD + vd);
                vreg1 = *(const short8*)(V + (nb + vr + 1) * DIM + h * HD + vd);
            }
        }

        // ---- P = exp2(S^T) in-register -> PV A-fragments (slot-permuted) ----
        short8 pfrag[2];
        const int kbase = kt * KT;
        if (kt >= nkt - 2) {
            const int qrow = q0 + wave * 16 + l15;
            float p[4][4];
#pragma unroll
            for (int n = 0; n < 4; ++n) {
                const int key0 = kbase + n * 16 + quad * 4;
#pragma unroll
                for (int r = 0; r < 4; ++r)
                    p[n][r] = (key0 + r <= qrow) ? EXP2(sT[n][r]) : 0.f;
            }
#pragma unroll
            for (int c = 0; c < 2; ++c) {
                short8 f;
#pragma unroll
                for (int j = 0; j < 8; ++j)
                    f[j] = f2s(p[c * 2 + (j >> 2)][j & 3]);
                pfrag[c] = f;
            }
        } else {
#pragma unroll
            for (int c = 0; c < 2; ++c) {
                short8 f;
#pragma unroll
                for (int j = 0; j < 8; ++j)
                    f[j] = f2s(EXP2(sT[c * 2 + (j >> 2)][j & 3]));
                pfrag[c] = f;
            }
        }

        // ---- O += P V ; l += P . 1 ----
#pragma unroll
        for (int n = 0; n < 4; ++n)
#pragma unroll
            for (int c = 0; c < 2; ++c) {
                short8 vf = *(const short8*)&Vt[b][n * 16 + l15][c * 32 + quad * 8];
                o_acc[n] = __builtin_amdgcn_mfma_f32_16x16x32_bf16(
                    pfrag[c], vf, o_acc[n], 0, 0, 0);
            }
        lacc = __builtin_amdgcn_mfma_f32_16x16x32_bf16(pfrag[0], onesf, lacc, 0, 0, 0);
        lacc = __builtin_amdgcn_mfma_f32_16x16x32_bf16(pfrag[1], onesf, lacc, 0, 0, 0);

        barrier_lgkm();   // buf[b^1] ds-visible; reads of buf[b] complete;
                          // kf/V global prefetches stay in flight
    }

    // ---- epilogue: O / l -> ctx ----
#pragma unroll
    for (int r = 0; r < 4; ++r) {
        const float inv = 1.0f / lacc[r];
        const int row = q0 + wave * 16 + quad * 4 + r;
#pragma unroll
        for (int n = 0; n < 4; ++n)
            ctx[(size_t)row * DIM + h * HD + n * 16 + l15] =
                __float2bfloat16(o_acc[n][r] * inv);
    }
#undef LOAD_KF
}

// ---------------------------------------------------------------------------
// Memory plan (16 MB ws):
//   ws[0 : 8MB]  = Wt_all (4 x bf16 [N][K]: Wq,Wk,Wv,Wo)
//   ws[8 : 16MB] = Q (bf16) -> ctx (in-place, alias-safe)
//   d_out[0:8MB] (bf16) = V scratch; d_out[8:16MB] = K scratch
// x is read directly (fp32) by the fused QKV GEMM — no cast, no alias.
// ---------------------------------------------------------------------------
extern "C" void kernel_launch(void* const* d_in, const int* in_sizes, int n_in,
                              void* d_out, int out_size, void* d_ws, size_t ws_size,
                              hipStream_t stream)
{
    const float* x  = (const float*)d_in[0];
    const float* Wq = (const float*)d_in[1];
    const float* Wk = (const float*)d_in[2];
    const float* Wv = (const float*)d_in[3];
    const float* Wo = (const float*)d_in[4];
    const float* bo = (const float*)d_in[5];
    float* out = (float*)d_out;

    bf16* Wt_all = (bf16*)d_ws;
    bf16* Qb     = Wt_all + (size_t)4 * DIM * DIM;    // ws + 8MB
    bf16* V      = (bf16*)d_out;                      // d_out[0:8MB]
    bf16* Kb     = V + (size_t)SEQ * DIM;             // d_out[8:16MB]
    bf16* ctx    = Qb;                                // in-place over Q
    const bf16* Wot = Wt_all + (size_t)3 * DIM * DIM;

    transpose_cast_kernel<<<dim3(32, 32, 4), 256, 0, stream>>>(Wq, Wk, Wv, Wo, Wt_all);

    qkv_gemm_kernel<<<dim3(DIM / QBN, SEQ / QBM, 3), 256, 0, stream>>>(
        x, Wt_all, Qb, Kb, V);

    flash_attn_kernel<<<dim3(32, NH), 512, 0, stream>>>(Qb, Kb, V, ctx);

    out_gemm_kernel<<<dim3(DIM / 64, SEQ / 128), 256, 0, stream>>>(
        ctx, Wot, bo, out);
}

// Round 9
// 184.299 us; speedup vs baseline: 1.4509x; 1.4509x over previous
//
#include <hip/hip_runtime.h>
#include <hip/hip_bf16.h>

typedef __hip_bfloat16 bf16;
typedef __attribute__((ext_vector_type(8))) short short8;   // 8 bf16 = 4 VGPRs
typedef __attribute__((ext_vector_type(4))) float floatx4;  // MFMA C/D

#define SEQ 4096
#define DIM 1024
#define NH 16
#define HD 64

// exp2 directly on v_exp_f32 (Q is pre-scaled by log2(e)/8 in projection)
#if defined(__has_builtin)
#if __has_builtin(__builtin_amdgcn_exp2f)
#define EXP2(x) __builtin_amdgcn_exp2f(x)
#endif
#endif
#ifndef EXP2
#define EXP2(x) exp2f(x)
#endif

__device__ __forceinline__ short f2s(float f) { bf16 t = __float2bfloat16(f); return *(short*)&t; }

// async global->LDS, 16B per lane; LDS dest = wave-uniform base + lane*16
__device__ __forceinline__ void gload16(const void* g, void* l) {
    __builtin_amdgcn_global_load_lds(
        (const __attribute__((address_space(1))) void*)g,
        (__attribute__((address_space(3))) void*)l, 16, 0, 0);
}

// Barrier that orders LDS ops only (no vmcnt drain): in-flight global->REG
// prefetch loads legally cross it; their consumers get compiler-inserted
// counted vmcnt waits. Writes drained BEFORE s_barrier => cross-wave visible.
__device__ __forceinline__ void barrier_lgkm() {
    asm volatile("s_waitcnt lgkmcnt(0)" ::: "memory");
    __builtin_amdgcn_s_barrier();
}

__device__ __forceinline__ short8 cvt8(float4 a, float4 b) {
    short8 s;
    s[0] = f2s(a.x); s[1] = f2s(a.y); s[2] = f2s(a.z); s[3] = f2s(a.w);
    s[4] = f2s(b.x); s[5] = f2s(b.y); s[6] = f2s(b.z); s[7] = f2s(b.w);
    return s;
}

// ---------------------------------------------------------------------------
// Transpose+cast: W fp32 [K][N] -> Wt bf16 [N][K]. blockIdx.z selects weight.
// ---------------------------------------------------------------------------
__global__ __launch_bounds__(256) void transpose_cast_kernel(
    const float* __restrict__ W0, const float* __restrict__ W1,
    const float* __restrict__ W2, const float* __restrict__ W3,
    bf16* __restrict__ Wt_all)
{
    const float* W = blockIdx.z == 0 ? W0 : blockIdx.z == 1 ? W1
                   : blockIdx.z == 2 ? W2 : W3;
    bf16* Wt = Wt_all + (size_t)blockIdx.z * DIM * DIM;

    __shared__ float tile[32][33];
    const int n0 = blockIdx.x * 32, k0 = blockIdx.y * 32;
    const int tr = threadIdx.x >> 5;
    const int tc = threadIdx.x & 31;
#pragma unroll
    for (int i = 0; i < 32; i += 8)
        tile[tr + i][tc] = W[(size_t)(k0 + tr + i) * DIM + n0 + tc];
    __syncthreads();
#pragma unroll
    for (int i = 0; i < 32; i += 8)
        Wt[(size_t)(n0 + tr + i) * DIM + k0 + tc] = __float2bfloat16(tile[tc][tr + i]);
}

// ---------------------------------------------------------------------------
// Fused QKV GEMM (round-1 version, measured good): C_z = x(fp32) @ Wt_z^T.
// 128x128 tile, BK=64, fp32-A DMA staging + cvt at fragment read, XOR swizzle.
// z==0 (Q) output pre-scaled by log2(e)/sqrt(HD) so attention uses raw exp2.
// ---------------------------------------------------------------------------
#define QBM 128
#define QBN 128
#define QBK 64

__global__ __launch_bounds__(256) void qkv_gemm_kernel(
    const float* __restrict__ A, const bf16* __restrict__ Wt,
    bf16* __restrict__ Qb, bf16* __restrict__ Kb, bf16* __restrict__ Vb)
{
    const int z = blockIdx.z;
    const bf16* Bt = Wt + (size_t)z * DIM * DIM;
    bf16* C = z == 0 ? Qb : (z == 1 ? Kb : Vb);
    const float osc = (z == 0) ? 0.18033688f : 1.0f;   // 0.125 * log2(e)

    __shared__ alignas(16) float Af[QBM][QBK];   // 32 KB, fp32
    __shared__ alignas(16) short Bs[QBN][QBK];   // 16 KB, bf16

    const int tid  = threadIdx.x;
    const int wave = tid >> 6, lane = tid & 63;
    const int l15  = lane & 15, quad = lane >> 4;
    const int wm = (wave & 1) * 64;
    const int wn = (wave >> 1) * 64;
    const int bm = blockIdx.y * QBM;
    const int bn = blockIdx.x * QBN;

    const int arow = tid >> 4;
    const int agch = (tid & 15) ^ (arow & 15);
    const float* gA = A + (size_t)(bm + arow) * DIM + agch * 4;
    char* ldsA = (char*)&Af[0][0] + wave * 1024;

    const int brow = tid >> 3;
    const int bgch = (tid & 7) ^ (brow & 7);
    const bf16* gB = Bt + (size_t)(bn + brow) * DIM + bgch * 8;
    char* ldsB = (char*)&Bs[0][0] + wave * 1024;

    floatx4 acc[4][4] = {};

    for (int k0 = 0; k0 < DIM; k0 += QBK) {
        __syncthreads();
#pragma unroll
        for (int c = 0; c < 8; ++c)
            gload16(gA + (size_t)c * 16 * DIM + k0, ldsA + c * 4096);
#pragma unroll
        for (int c = 0; c < 4; ++c)
            gload16(gB + (size_t)c * 32 * DIM + k0, ldsB + c * 4096);
        __syncthreads();

#pragma unroll
        for (int c2 = 0; c2 < 2; ++c2) {
            const int g0 = c2 * 8 + quad * 2;
            const int cb = (c2 * 4 + quad) ^ (l15 & 7);
            short8 afr[4], bfr[4];
#pragma unroll
            for (int i = 0; i < 4; ++i) {
                const int ra = wm + i * 16 + l15;
                float4 f0 = *(const float4*)&Af[ra][(g0 ^ l15) * 4];
                float4 f1 = *(const float4*)&Af[ra][((g0 + 1) ^ l15) * 4];
                afr[i] = cvt8(f0, f1);
                bfr[i] = *(const short8*)&Bs[wn + i * 16 + l15][cb * 8];
            }
#pragma unroll
            for (int mi = 0; mi < 4; ++mi)
#pragma unroll
                for (int ni = 0; ni < 4; ++ni)
                    acc[mi][ni] = __builtin_amdgcn_mfma_f32_16x16x32_bf16(
                        afr[mi], bfr[ni], acc[mi][ni], 0, 0, 0);
        }
    }

#pragma unroll
    for (int mi = 0; mi < 4; ++mi)
#pragma unroll
        for (int r = 0; r < 4; ++r) {
            const int row = bm + wm + mi * 16 + quad * 4 + r;
#pragma unroll
            for (int ni = 0; ni < 4; ++ni) {
                const int col = bn + wn + ni * 16 + l15;
                C[(size_t)row * DIM + col] = __float2bfloat16(acc[mi][ni][r] * osc);
            }
        }
}

// ---------------------------------------------------------------------------
// Final GEMM (unchanged): out = ctx(bf16) @ Wo^T + bias. 128x64 tile.
// ---------------------------------------------------------------------------
__global__ __launch_bounds__(256) void out_gemm_kernel(
    const bf16* __restrict__ A, const bf16* __restrict__ Bt,
    const float* __restrict__ bias, float* __restrict__ C)
{
    __shared__ alignas(16) short Asl[128][64];
    __shared__ alignas(16) short Bsl[64][64];

    const int tid  = threadIdx.x;
    const int wave = tid >> 6, lane = tid & 63;
    const int l15  = lane & 15, quad = lane >> 4;
    const int wm = (wave & 1) * 64;
    const int wn = (wave >> 1) * 32;
    const int bm = blockIdx.y * 128;
    const int bn = blockIdx.x * 64;

    const int srow   = tid >> 3;
    const int gchunk = (tid & 7) ^ (srow & 7);
    const bf16* gA = A  + (size_t)(bm + srow) * DIM + gchunk * 8;
    const bf16* gB = Bt + (size_t)(bn + srow) * DIM + gchunk * 8;
    char* ldsA = (char*)&Asl[0][0] + wave * 1024;
    char* ldsB = (char*)&Bsl[0][0] + wave * 1024;

    floatx4 acc[4][2] = {};

    for (int k0 = 0; k0 < DIM; k0 += 64) {
        __syncthreads();
#pragma unroll
        for (int c = 0; c < 4; ++c)
            gload16(gA + (size_t)c * 32 * DIM + k0, ldsA + c * 4096);
#pragma unroll
        for (int c = 0; c < 2; ++c)
            gload16(gB + (size_t)c * 32 * DIM + k0, ldsB + c * 4096);
        __syncthreads();

#pragma unroll
        for (int c2 = 0; c2 < 2; ++c2) {
            const int cb = (c2 * 4 + quad) ^ (l15 & 7);
            short8 afr[4], bfr[2];
#pragma unroll
            for (int i = 0; i < 4; ++i)
                afr[i] = *(const short8*)&Asl[wm + i * 16 + l15][cb * 8];
#pragma unroll
            for (int i = 0; i < 2; ++i)
                bfr[i] = *(const short8*)&Bsl[wn + i * 16 + l15][cb * 8];
#pragma unroll
            for (int mi = 0; mi < 4; ++mi)
#pragma unroll
                for (int ni = 0; ni < 2; ++ni)
                    acc[mi][ni] = __builtin_amdgcn_mfma_f32_16x16x32_bf16(
                        afr[mi], bfr[ni], acc[mi][ni], 0, 0, 0);
        }
    }

#pragma unroll
    for (int mi = 0; mi < 4; ++mi)
#pragma unroll
        for (int r = 0; r < 4; ++r) {
            const int row = bm + wm + mi * 16 + quad * 4 + r;
#pragma unroll
            for (int ni = 0; ni < 2; ++ni) {
                const int col = bn + wn + ni * 16 + l15;
                C[(size_t)row * DIM + col] = acc[mi][ni][r] + bias[col];
            }
        }
}

// ---------------------------------------------------------------------------
// Flash attention v13: KEY-SPLIT WAVES to halve LDS bytes per unit work.
// 8 waves = 4 q-groups (32 rows, covering QT=128) x 2 KEY-HALVES (32 keys).
// Each wave computes S^T/exp/PV only for ITS 32 keys of each K-tile, so it
// reads half the K tile (4KB) and half the V tile (4KB): per block-tile
// LDS reads = 64KB (was 128KB in round 6), floor ~1250cy (was 2250).
// PV sums over keys => the two key-half partial O/l accumulators are exact
// partials; merged ONCE at the end via LDS (reuses the K/V buffers, one
// extra barrier). Per-wave work halves (18 MFMA, 16 exp2).
// V-slot permutation per 32-key half: slot = [k3 k2 k4 k1 k0] so each lane's
// 8 P values land in its own PV A-slots. K in LDS (round-8 global-K failed:
// VMEM latency), reg-staged, double-buffered, lgkm-only barriers, exp2 path,
// complementary pairing. launch_bounds(512,4) keeps VGPR<=128 so paired
// blocks hold 4 waves/SIMD.
// ---------------------------------------------------------------------------
#define QT 128
#define KT 64
#define LDT 72

__global__ __launch_bounds__(512, 4) void flash_attn_kernel(
    const bf16* __restrict__ Q, const bf16* __restrict__ K,
    const bf16* __restrict__ V, bf16* ctx)
{
    const int lin  = blockIdx.y * 32 + blockIdx.x;
    const int half = lin >> 8, idx = lin & 255;
    const int qj   = half ? (idx & 31) : 31 - (idx & 31);
    const int h    = (idx >> 5) + 8 * half;
    const int q0   = qj * QT;
    const int nkt  = 2 * qj + 2;

    const int tid  = threadIdx.x;          // 0..511
    const int wave = tid >> 6;             // 0..7
    const int qg   = wave & 3;             // q-row group: rows qg*32..+31
    const int kh   = wave >> 2;            // key half: keys kh*32..+31
    const int lane = tid & 63;
    const int l15  = lane & 15;
    const int quad = lane >> 4;

    // K/V double buffers; after the loop the same space is reused for the
    // cross-half O/l reduction (32KB + 512B <= 36864B).
    __shared__ alignas(16) char smem[36864];
    short (*Ks)[KT][LDT] = (short (*)[KT][LDT])smem;            // [2][64][72]
    short (*Vt)[HD][LDT] = (short (*)[HD][LDT])(smem + 18432);  // [2][64][72]
    float* redO = (float*)smem;            // 8192 floats = 32 KB
    float* redL = (float*)(smem + 32768);  // 128 floats

    // ---- Q fragments straight from global (no LDS); 32 rows per wave ----
    short8 qfrag[2][2];
#pragma unroll
    for (int s = 0; s < 2; ++s) {
        const bf16* qp = Q + (size_t)(q0 + qg * 32 + s * 16 + l15) * DIM
                       + h * HD + quad * 8;
        qfrag[s][0] = *(const short8*)(qp);
        qfrag[s][1] = *(const short8*)(qp + 32);
    }

    // K staging: 512 threads, one 16B unit: row tid>>3 (0..63), chunk (tid&7)*8
    const int kr = tid >> 3, kc = (tid & 7) * 8;
    // V staging: threads 0..255 (keys vr,vr+1 x dims vd..vd+7)
    const bool vstager = tid < 256;
    const int vr = (tid & 31) * 2, vd = ((tid >> 5) & 7) * 8;
    // key -> PV slot within its 32-key half: slot = [k3 k2 | k4 | k1 k0]
    // column = (key & 32) + slot. vr even => consecutive key pair -> ++col.
    const int vcol = (vr & 32) + ((vr >> 2) & 3) * 8
                   + ((vr >> 4) & 1) * 4 + (vr & 3);

    // ---- load tile 0 regs, write straight to buf0 ----
    short8 kreg, vreg0, vreg1;
    kreg = *(const short8*)(K + (size_t)kr * DIM + h * HD + kc);
    if (vstager) {
        vreg0 = *(const short8*)(V + (size_t)vr * DIM + h * HD + vd);
        vreg1 = *(const short8*)(V + (size_t)(vr + 1) * DIM + h * HD + vd);
    }
    *(short8*)&Ks[0][kr][kc] = kreg;
    if (vstager) {
#pragma unroll
        for (int i = 0; i < 8; ++i) {
            unsigned int pv = (unsigned int)(unsigned short)vreg0[i]
                            | ((unsigned int)(unsigned short)vreg1[i] << 16);
            *(unsigned int*)&Vt[0][vd + i][vcol] = pv;
        }
    }
    // ---- prefetch tile 1 regs (nkt >= 2 always) ----
    kreg = *(const short8*)(K + (size_t)(KT + kr) * DIM + h * HD + kc);
    if (vstager) {
        vreg0 = *(const short8*)(V + (size_t)(KT + vr) * DIM + h * HD + vd);
        vreg1 = *(const short8*)(V + (size_t)(KT + vr + 1) * DIM + h * HD + vd);
    }

    barrier_lgkm();   // buf0 ds_writes visible; tile-1 loads stay in flight

    short8 onesf;
#pragma unroll
    for (int i = 0; i < 8; ++i) onesf[i] = (short)0x3F80;   // bf16 1.0

    floatx4 o_acc[2][4] = {};
    floatx4 lacc[2] = {};

    for (int kt = 0; kt < nkt; ++kt) {
        const int b = kt & 1;

        // ---- S^T (this wave's 32 keys): D[m=key kh*32+n*16+quad*4+r][qrow l15]
        floatx4 sT[2][2] = {};
#pragma unroll
        for (int n = 0; n < 2; ++n)
#pragma unroll
            for (int c = 0; c < 2; ++c) {
                short8 kf = *(const short8*)
                    &Ks[b][kh * 32 + n * 16 + l15][c * 32 + quad * 8];
#pragma unroll
                for (int s = 0; s < 2; ++s)
                    sT[s][n] = __builtin_amdgcn_mfma_f32_16x16x32_bf16(
                        kf, qfrag[s][c], sT[s][n], 0, 0, 0);
            }

        // ---- stage tile kt+1 into buf[b^1] early; prefetch tile kt+2 ----
        if (kt + 1 < nkt) {
            *(short8*)&Ks[b ^ 1][kr][kc] = kreg;
            if (vstager) {
#pragma unroll
                for (int i = 0; i < 8; ++i) {
                    unsigned int pv = (unsigned int)(unsigned short)vreg0[i]
                                    | ((unsigned int)(unsigned short)vreg1[i] << 16);
                    *(unsigned int*)&Vt[b ^ 1][vd + i][vcol] = pv;
                }
            }
            if (kt + 2 < nkt) {
                const size_t nb = (size_t)(kt + 2) * KT;
                kreg = *(const short8*)(K + (nb + kr) * DIM + h * HD + kc);
                if (vstager) {
                    vreg0 = *(const short8*)(V + (nb + vr) * DIM + h * HD + vd);
                    vreg1 = *(const short8*)(V + (nb + vr + 1) * DIM + h * HD + vd);
                }
            }
        }

        // ---- P = exp2(S^T) in-register -> PV A-fragment (slot j = n*4+r) ----
        short8 pfrag[2];
        const int kbase = kt * KT + kh * 32;
        if (kt >= nkt - 2) {
#pragma unroll
            for (int s = 0; s < 2; ++s) {
                const int qrow = q0 + qg * 32 + s * 16 + l15;
                float p[2][4];
#pragma unroll
                for (int n = 0; n < 2; ++n) {
                    const int key0 = kbase + n * 16 + quad * 4;
#pragma unroll
                    for (int r = 0; r < 4; ++r)
                        p[n][r] = (key0 + r <= qrow) ? EXP2(sT[s][n][r]) : 0.f;
                }
                short8 f;
#pragma unroll
                for (int j = 0; j < 8; ++j)
                    f[j] = f2s(p[j >> 2][j & 3]);
                pfrag[s] = f;
            }
        } else {
#pragma unroll
            for (int s = 0; s < 2; ++s) {
                short8 f;
#pragma unroll
                for (int j = 0; j < 8; ++j)
                    f[j] = f2s(EXP2(sT[s][j >> 2][j & 3]));
                pfrag[s] = f;
            }
        }

        // ---- O += P V (this key half only) ; l += P . 1 ----
#pragma unroll
        for (int n = 0; n < 4; ++n) {
            short8 vf = *(const short8*)
                &Vt[b][n * 16 + l15][kh * 32 + quad * 8];
#pragma unroll
            for (int s = 0; s < 2; ++s)
                o_acc[s][n] = __builtin_amdgcn_mfma_f32_16x16x32_bf16(
                    pfrag[s], vf, o_acc[s][n], 0, 0, 0);
        }
#pragma unroll
        for (int s = 0; s < 2; ++s)
            lacc[s] = __builtin_amdgcn_mfma_f32_16x16x32_bf16(
                pfrag[s], onesf, lacc[s], 0, 0, 0);

        barrier_lgkm();   // buf[b^1] ds-visible; reads of buf[b] complete;
                          // kt+2 global prefetch stays in flight
    }

    // ---- cross-half reduction: kh=1 partials -> LDS -> kh=0 adds ----
    if (kh == 1) {
#pragma unroll
        for (int s = 0; s < 2; ++s)
#pragma unroll
            for (int n = 0; n < 4; ++n)
#pragma unroll
                for (int r = 0; r < 4; ++r)
                    redO[(size_t)(qg * 32 + s * 16 + quad * 4 + r) * 64
                         + n * 16 + l15] = o_acc[s][n][r];
        if (l15 == 0) {
#pragma unroll
            for (int s = 0; s < 2; ++s)
#pragma unroll
                for (int r = 0; r < 4; ++r)
                    redL[qg * 32 + s * 16 + quad * 4 + r] = lacc[s][r];
        }
    }
    __syncthreads();
    if (kh == 0) {
#pragma unroll
        for (int s = 0; s < 2; ++s)
#pragma unroll
            for (int r = 0; r < 4; ++r) {
                const int row_l = qg * 32 + s * 16 + quad * 4 + r;
                const float lsum = lacc[s][r] + redL[row_l];
                const float inv = 1.0f / lsum;
                const int row = q0 + row_l;
#pragma unroll
                for (int n = 0; n < 4; ++n) {
                    const float o = o_acc[s][n][r]
                                  + redO[(size_t)row_l * 64 + n * 16 + l15];
                    ctx[(size_t)row * DIM + h * HD + n * 16 + l15] =
                        __float2bfloat16(o * inv);
                }
            }
    }
}

// ---------------------------------------------------------------------------
// Memory plan (16 MB ws):
//   ws[0 : 8MB]  = Wt_all (4 x bf16 [N][K]: Wq,Wk,Wv,Wo)
//   ws[8 : 16MB] = Q (bf16) -> ctx (in-place, alias-safe)
//   d_out[0:8MB] (bf16) = V scratch; d_out[8:16MB] = K scratch
// x is read directly (fp32) by the fused QKV GEMM — no cast, no alias.
// ---------------------------------------------------------------------------
extern "C" void kernel_launch(void* const* d_in, const int* in_sizes, int n_in,
                              void* d_out, int out_size, void* d_ws, size_t ws_size,
                              hipStream_t stream)
{
    const float* x  = (const float*)d_in[0];
    const float* Wq = (const float*)d_in[1];
    const float* Wk = (const float*)d_in[2];
    const float* Wv = (const float*)d_in[3];
    const float* Wo = (const float*)d_in[4];
    const float* bo = (const float*)d_in[5];
    float* out = (float*)d_out;

    bf16* Wt_all = (bf16*)d_ws;
    bf16* Qb     = Wt_all + (size_t)4 * DIM * DIM;    // ws + 8MB
    bf16* V      = (bf16*)d_out;                      // d_out[0:8MB]
    bf16* Kb     = V + (size_t)SEQ * DIM;             // d_out[8:16MB]
    bf16* ctx    = Qb;                                // in-place over Q
    const bf16* Wot = Wt_all + (size_t)3 * DIM * DIM;

    transpose_cast_kernel<<<dim3(32, 32, 4), 256, 0, stream>>>(Wq, Wk, Wv, Wo, Wt_all);

    qkv_gemm_kernel<<<dim3(DIM / QBN, SEQ / QBM, 3), 256, 0, stream>>>(
        x, Wt_all, Qb, Kb, V);

    flash_attn_kernel<<<dim3(32, NH), 512, 0, stream>>>(Qb, Kb, V, ctx);

    out_gemm_kernel<<<dim3(DIM / 64, SEQ / 128), 256, 0, stream>>>(
        ctx, Wot, bo, out);
}